// Round 1
// baseline (217.266 us; speedup 1.0000x reference)
//
#include <hip/hip_runtime.h>

// Forward kinematics, H36M 17-joint skeleton.
// One thread = one sample. Coalesced global<->LDS staging on both sides.
// LDS: euler staged at stride 51 (odd -> conflict-free per-thread reads),
//      output staged at natural stride 51 (odd -> conflict-free writes,
//      flat-contiguous -> float4 coalesced stores).
// 128 threads/block, 52224 B LDS -> 3 blocks/CU (6 waves/CU).

#define NB 128

__device__ __forceinline__ void mm3(const float A[9], const float B[9], float C[9]) {
#pragma unroll
    for (int r = 0; r < 3; ++r) {
        C[3*r+0] = A[3*r+0]*B[0] + A[3*r+1]*B[3] + A[3*r+2]*B[6];
        C[3*r+1] = A[3*r+0]*B[1] + A[3*r+1]*B[4] + A[3*r+2]*B[7];
        C[3*r+2] = A[3*r+0]*B[2] + A[3*r+1]*B[5] + A[3*r+2]*B[8];
    }
}

// R = Rx(a) @ Ry(b) @ Rz(c)  (pytorch3d euler_angles_to_matrix 'XYZ'), row-major
__device__ __forceinline__ void euler_rot(const float* __restrict__ e, int i, float R[9]) {
    float a = e[3*i+0], b = e[3*i+1], c = e[3*i+2];
    float sx, cx, sy, cy, sz, cz;
    __sincosf(a, &sx, &cx);
    __sincosf(b, &sy, &cy);
    __sincosf(c, &sz, &cz);
    R[0] = cy*cz;             R[1] = -cy*sz;            R[2] = sy;
    R[3] = sx*sy*cz + cx*sz;  R[4] = -sx*sy*sz + cx*cz; R[5] = -sx*cy;
    R[6] = -cx*sy*cz + sx*sz; R[7] = cx*sy*sz + sx*cz;  R[8] = cx*cy;
}

__global__ void __launch_bounds__(NB)
fk17_kernel(const float* __restrict__ euler, const float* __restrict__ blen,
            float* __restrict__ out, int n)
{
    __shared__ float s_e[NB * 51];  // 48 used + 3 pad per sample
    __shared__ float s_o[NB * 51];  // 17 joints * 3, naturally odd stride

    const int tid    = threadIdx.x;
    const int block0 = blockIdx.x * NB;
    const int nvalid = min(NB, n - block0);

    // ---- bone lengths: per-thread vector loads straight to registers ----
    float L[16];
    if (tid < nvalid) {
        const float4* gb4 = (const float4*)(blen + (size_t)(block0 + tid) * 16);
#pragma unroll
        for (int q = 0; q < 4; ++q) {
            float4 v = gb4[q];
            L[4*q+0] = v.x; L[4*q+1] = v.y; L[4*q+2] = v.z; L[4*q+3] = v.w;
        }
    }

    // ---- euler: coalesced float4 global loads -> stride-51 LDS ----
    const float4* ge4 = (const float4*)(euler + (size_t)block0 * 48);
    const int ne4 = nvalid * 12;
    for (int i4 = tid; i4 < ne4; i4 += NB) {
        float4 v = ge4[i4];
        int s = i4 / 12;
        int k = (i4 - s * 12) * 4;
        float* dst = s_e + s * 51 + k;
        dst[0] = v.x; dst[1] = v.y; dst[2] = v.z; dst[3] = v.w;
    }
    __syncthreads();

    // ---- per-sample kinematic chain ----
    if (tid < nvalid) {
        const float* e = s_e + tid * 51;
        float*       o = s_o + tid * 51;
        float Ma[9], Mb[9], M8[9], R[9];
        float px, py, pz, p8x, p8y, p8z;

        // root (joint 0)
        o[0] = 0.f; o[1] = 0.f; o[2] = 0.f;

        // --- chain: 0 -> 1 -> 2 -> 3 (bones 0,1,2) ---
        euler_rot(e, 0, Ma);                        // M1 = I @ R0
        px = L[0]*Ma[6]; py = L[0]*Ma[7]; pz = L[0]*Ma[8];
        o[3] = px; o[4] = py; o[5] = pz;
        euler_rot(e, 1, R); mm3(Ma, R, Mb);
        px += L[1]*Mb[6]; py += L[1]*Mb[7]; pz += L[1]*Mb[8];
        o[6] = px; o[7] = py; o[8] = pz;
        euler_rot(e, 2, R); mm3(Mb, R, Ma);
        px += L[2]*Ma[6]; py += L[2]*Ma[7]; pz += L[2]*Ma[8];
        o[9] = px; o[10] = py; o[11] = pz;

        // --- chain: 0 -> 4 -> 5 -> 6 (bones 3,4,5) ---
        euler_rot(e, 3, Ma);
        px = L[3]*Ma[6]; py = L[3]*Ma[7]; pz = L[3]*Ma[8];
        o[12] = px; o[13] = py; o[14] = pz;
        euler_rot(e, 4, R); mm3(Ma, R, Mb);
        px += L[4]*Mb[6]; py += L[4]*Mb[7]; pz += L[4]*Mb[8];
        o[15] = px; o[16] = py; o[17] = pz;
        euler_rot(e, 5, R); mm3(Mb, R, Ma);
        px += L[5]*Ma[6]; py += L[5]*Ma[7]; pz += L[5]*Ma[8];
        o[18] = px; o[19] = py; o[20] = pz;

        // --- spine: 0 -> 7 -> 8 (bones 6,7) ---
        euler_rot(e, 6, Ma);
        px = L[6]*Ma[6]; py = L[6]*Ma[7]; pz = L[6]*Ma[8];
        o[21] = px; o[22] = py; o[23] = pz;
        euler_rot(e, 7, R); mm3(Ma, R, M8);         // M8 = accum at joint 8
        px += L[7]*M8[6]; py += L[7]*M8[7]; pz += L[7]*M8[8];
        o[24] = px; o[25] = py; o[26] = pz;
        p8x = px; p8y = py; p8z = pz;

        // --- branch: 8 -> 9 -> 10 (bones 8,9) ---
        euler_rot(e, 8, R); mm3(M8, R, Ma);
        px = p8x + L[8]*Ma[6]; py = p8y + L[8]*Ma[7]; pz = p8z + L[8]*Ma[8];
        o[27] = px; o[28] = py; o[29] = pz;
        euler_rot(e, 9, R); mm3(Ma, R, Mb);
        px += L[9]*Mb[6]; py += L[9]*Mb[7]; pz += L[9]*Mb[8];
        o[30] = px; o[31] = py; o[32] = pz;

        // --- branch: 8 -> 11 -> 12 -> 13 (bones 10,11,12) ---
        euler_rot(e, 10, R); mm3(M8, R, Ma);
        px = p8x + L[10]*Ma[6]; py = p8y + L[10]*Ma[7]; pz = p8z + L[10]*Ma[8];
        o[33] = px; o[34] = py; o[35] = pz;
        euler_rot(e, 11, R); mm3(Ma, R, Mb);
        px += L[11]*Mb[6]; py += L[11]*Mb[7]; pz += L[11]*Mb[8];
        o[36] = px; o[37] = py; o[38] = pz;
        euler_rot(e, 12, R); mm3(Mb, R, Ma);
        px += L[12]*Ma[6]; py += L[12]*Ma[7]; pz += L[12]*Ma[8];
        o[39] = px; o[40] = py; o[41] = pz;

        // --- branch: 8 -> 14 -> 15 -> 16 (bones 13,14,15) ---
        euler_rot(e, 13, R); mm3(M8, R, Ma);
        px = p8x + L[13]*Ma[6]; py = p8y + L[13]*Ma[7]; pz = p8z + L[13]*Ma[8];
        o[42] = px; o[43] = py; o[44] = pz;
        euler_rot(e, 14, R); mm3(Ma, R, Mb);
        px += L[14]*Mb[6]; py += L[14]*Mb[7]; pz += L[14]*Mb[8];
        o[45] = px; o[46] = py; o[47] = pz;
        euler_rot(e, 15, R); mm3(Mb, R, Ma);
        px += L[15]*Ma[6]; py += L[15]*Ma[7]; pz += L[15]*Ma[8];
        o[48] = px; o[49] = py; o[50] = pz;
    }
    __syncthreads();

    // ---- coalesced store: LDS flat -> global ----
    float* og = out + (size_t)block0 * 51;
    if (nvalid == NB) {
        const float4* so4 = (const float4*)s_o;
        float4*       og4 = (float4*)og;
        for (int i4 = tid; i4 < NB * 51 / 4; i4 += NB)  // 1632 float4s
            og4[i4] = so4[i4];
    } else {
        const int tot = nvalid * 51;
        for (int i = tid; i < tot; i += NB)
            og[i] = s_o[i];
    }
}

extern "C" void kernel_launch(void* const* d_in, const int* in_sizes, int n_in,
                              void* d_out, int out_size, void* d_ws, size_t ws_size,
                              hipStream_t stream) {
    const float* euler = (const float*)d_in[0];   // (N,16,3) fp32
    const float* blen  = (const float*)d_in[1];   // (N,16,1) fp32
    float* out = (float*)d_out;                   // (N,17,3) fp32

    const int n    = in_sizes[0] / 48;
    const int grid = (n + NB - 1) / NB;
    fk17_kernel<<<grid, NB, 0, stream>>>(euler, blen, out, n);
}

// Round 2
// 201.603 us; speedup vs baseline: 1.0777x; 1.0777x over previous
//
#include <hip/hip_runtime.h>

// Forward kinematics, H36M 17-joint skeleton.
// One thread = one sample. SINGLE shared buffer reused for euler staging and
// output staging (each thread only touches its own 51-float slice between the
// two barriers, so no extra sync needed for the overwrite).
// LDS: 128 * 51 * 4 = 26112 B -> 6 blocks/CU = 12 waves/CU (2x round 1).
// Eulers pulled into registers before compute so all 16 sincos groups are
// independent (ILP against the serial matrix chain).

#define NB 128

__device__ __forceinline__ void mm3(const float A[9], const float B[9], float C[9]) {
#pragma unroll
    for (int r = 0; r < 3; ++r) {
        C[3*r+0] = A[3*r+0]*B[0] + A[3*r+1]*B[3] + A[3*r+2]*B[6];
        C[3*r+1] = A[3*r+0]*B[1] + A[3*r+1]*B[4] + A[3*r+2]*B[7];
        C[3*r+2] = A[3*r+0]*B[2] + A[3*r+1]*B[5] + A[3*r+2]*B[8];
    }
}

// R = Rx(a) @ Ry(b) @ Rz(c)  (pytorch3d euler_angles_to_matrix 'XYZ'), row-major
__device__ __forceinline__ void euler_rot(const float* __restrict__ ev, int i, float R[9]) {
    float a = ev[3*i+0], b = ev[3*i+1], c = ev[3*i+2];
    float sx, cx, sy, cy, sz, cz;
    __sincosf(a, &sx, &cx);
    __sincosf(b, &sy, &cy);
    __sincosf(c, &sz, &cz);
    R[0] = cy*cz;             R[1] = -cy*sz;            R[2] = sy;
    R[3] = sx*sy*cz + cx*sz;  R[4] = -sx*sy*sz + cx*cz; R[5] = -sx*cy;
    R[6] = -cx*sy*cz + sx*sz; R[7] = cx*sy*sz + sx*cz;  R[8] = cx*cy;
}

__global__ void __launch_bounds__(NB, 3)
fk17_kernel(const float* __restrict__ euler, const float* __restrict__ blen,
            float* __restrict__ out, int n)
{
    __shared__ float s[NB * 51];  // euler staging (48/51 used), then output staging

    const int tid    = threadIdx.x;
    const int block0 = blockIdx.x * NB;
    const int nvalid = min(NB, n - block0);

    // ---- bone lengths: per-thread vector loads straight to registers ----
    float L[16];
    if (tid < nvalid) {
        const float4* gb4 = (const float4*)(blen + (size_t)(block0 + tid) * 16);
#pragma unroll
        for (int q = 0; q < 4; ++q) {
            float4 v = gb4[q];
            L[4*q+0] = v.x; L[4*q+1] = v.y; L[4*q+2] = v.z; L[4*q+3] = v.w;
        }
    }

    // ---- euler: coalesced float4 global loads -> stride-51 LDS ----
    {
        const float4* ge4 = (const float4*)(euler + (size_t)block0 * 48);
        const int ne4 = nvalid * 12;
        for (int i4 = tid; i4 < ne4; i4 += NB) {
            float4 v = ge4[i4];
            int smp = i4 / 12;
            int k   = (i4 - smp * 12) * 4;
            float* dst = s + smp * 51 + k;
            dst[0] = v.x; dst[1] = v.y; dst[2] = v.z; dst[3] = v.w;
        }
    }
    __syncthreads();

    // ---- per-sample kinematic chain (own slice only: read -> regs -> overwrite) ----
    if (tid < nvalid) {
        float* o = s + tid * 51;

        // pull all 48 eulers into registers (frees the slice for output reuse,
        // and exposes all 16 sincos groups as independent work)
        float ev[48];
#pragma unroll
        for (int i = 0; i < 48; ++i) ev[i] = o[i];

        float Ma[9], Mb[9], M8[9], R[9];
        float px, py, pz, p8x, p8y, p8z;

        // root (joint 0)
        o[0] = 0.f; o[1] = 0.f; o[2] = 0.f;

        // --- chain: 0 -> 1 -> 2 -> 3 (bones 0,1,2) ---
        euler_rot(ev, 0, Ma);                        // M1 = I @ R0
        px = L[0]*Ma[6]; py = L[0]*Ma[7]; pz = L[0]*Ma[8];
        o[3] = px; o[4] = py; o[5] = pz;
        euler_rot(ev, 1, R); mm3(Ma, R, Mb);
        px += L[1]*Mb[6]; py += L[1]*Mb[7]; pz += L[1]*Mb[8];
        o[6] = px; o[7] = py; o[8] = pz;
        euler_rot(ev, 2, R); mm3(Mb, R, Ma);
        px += L[2]*Ma[6]; py += L[2]*Ma[7]; pz += L[2]*Ma[8];
        o[9] = px; o[10] = py; o[11] = pz;

        // --- chain: 0 -> 4 -> 5 -> 6 (bones 3,4,5) ---
        euler_rot(ev, 3, Ma);
        px = L[3]*Ma[6]; py = L[3]*Ma[7]; pz = L[3]*Ma[8];
        o[12] = px; o[13] = py; o[14] = pz;
        euler_rot(ev, 4, R); mm3(Ma, R, Mb);
        px += L[4]*Mb[6]; py += L[4]*Mb[7]; pz += L[4]*Mb[8];
        o[15] = px; o[16] = py; o[17] = pz;
        euler_rot(ev, 5, R); mm3(Mb, R, Ma);
        px += L[5]*Ma[6]; py += L[5]*Ma[7]; pz += L[5]*Ma[8];
        o[18] = px; o[19] = py; o[20] = pz;

        // --- spine: 0 -> 7 -> 8 (bones 6,7) ---
        euler_rot(ev, 6, Ma);
        px = L[6]*Ma[6]; py = L[6]*Ma[7]; pz = L[6]*Ma[8];
        o[21] = px; o[22] = py; o[23] = pz;
        euler_rot(ev, 7, R); mm3(Ma, R, M8);         // M8 = accum at joint 8
        px += L[7]*M8[6]; py += L[7]*M8[7]; pz += L[7]*M8[8];
        o[24] = px; o[25] = py; o[26] = pz;
        p8x = px; p8y = py; p8z = pz;

        // --- branch: 8 -> 9 -> 10 (bones 8,9) ---
        euler_rot(ev, 8, R); mm3(M8, R, Ma);
        px = p8x + L[8]*Ma[6]; py = p8y + L[8]*Ma[7]; pz = p8z + L[8]*Ma[8];
        o[27] = px; o[28] = py; o[29] = pz;
        euler_rot(ev, 9, R); mm3(Ma, R, Mb);
        px += L[9]*Mb[6]; py += L[9]*Mb[7]; pz += L[9]*Mb[8];
        o[30] = px; o[31] = py; o[32] = pz;

        // --- branch: 8 -> 11 -> 12 -> 13 (bones 10,11,12) ---
        euler_rot(ev, 10, R); mm3(M8, R, Ma);
        px = p8x + L[10]*Ma[6]; py = p8y + L[10]*Ma[7]; pz = p8z + L[10]*Ma[8];
        o[33] = px; o[34] = py; o[35] = pz;
        euler_rot(ev, 11, R); mm3(Ma, R, Mb);
        px += L[11]*Mb[6]; py += L[11]*Mb[7]; pz += L[11]*Mb[8];
        o[36] = px; o[37] = py; o[38] = pz;
        euler_rot(ev, 12, R); mm3(Mb, R, Ma);
        px += L[12]*Ma[6]; py += L[12]*Ma[7]; pz += L[12]*Ma[8];
        o[39] = px; o[40] = py; o[41] = pz;

        // --- branch: 8 -> 14 -> 15 -> 16 (bones 13,14,15) ---
        euler_rot(ev, 13, R); mm3(M8, R, Ma);
        px = p8x + L[13]*Ma[6]; py = p8y + L[13]*Ma[7]; pz = p8z + L[13]*Ma[8];
        o[42] = px; o[43] = py; o[44] = pz;
        euler_rot(ev, 14, R); mm3(Ma, R, Mb);
        px += L[14]*Mb[6]; py += L[14]*Mb[7]; pz += L[14]*Mb[8];
        o[45] = px; o[46] = py; o[47] = pz;
        euler_rot(ev, 15, R); mm3(Mb, R, Ma);
        px += L[15]*Ma[6]; py += L[15]*Ma[7]; pz += L[15]*Ma[8];
        o[48] = px; o[49] = py; o[50] = pz;
    }
    __syncthreads();

    // ---- coalesced store: LDS flat -> global ----
    float* og = out + (size_t)block0 * 51;
    if (nvalid == NB) {
        const float4* so4 = (const float4*)s;
        float4*       og4 = (float4*)og;
        for (int i4 = tid; i4 < NB * 51 / 4; i4 += NB)  // 1632 float4s
            og4[i4] = so4[i4];
    } else {
        const int tot = nvalid * 51;
        for (int i = tid; i < tot; i += NB)
            og[i] = s[i];
    }
}

extern "C" void kernel_launch(void* const* d_in, const int* in_sizes, int n_in,
                              void* d_out, int out_size, void* d_ws, size_t ws_size,
                              hipStream_t stream) {
    const float* euler = (const float*)d_in[0];   // (N,16,3) fp32
    const float* blen  = (const float*)d_in[1];   // (N,16,1) fp32
    float* out = (float*)d_out;                   // (N,17,3) fp32

    const int n    = in_sizes[0] / 48;
    const int grid = (n + NB - 1) / NB;
    fk17_kernel<<<grid, NB, 0, stream>>>(euler, blen, out, n);
}

// Round 3
// 200.647 us; speedup vs baseline: 1.0828x; 1.0048x over previous
//
#include <hip/hip_runtime.h>

// Forward kinematics, H36M 17-joint skeleton.
// One thread = one sample.
// R3 change: euler angles loaded DIRECTLY per-thread (12 independent float4
// global loads, 16B-aligned, wave spans one contiguous 12KB region) instead of
// the staged LDS path — round-2's staging loop had a data-dependent trip count
// and compiled to 12 serialized load->waitcnt(0)->ds_write HBM round-trips per
// thread (~4.5us latency/wave), which 12 waves/CU could not hide.
// Output keeps LDS staging + coalesced float4 stores (proven: WRITE_SIZE ==
// exact output bytes, no write-allocate overfetch).
// LDS: 128*51*4 = 26112 B -> 6 blocks/CU = 12 waves/CU.

#define NB 128

__device__ __forceinline__ void mm3(const float A[9], const float B[9], float C[9]) {
#pragma unroll
    for (int r = 0; r < 3; ++r) {
        C[3*r+0] = A[3*r+0]*B[0] + A[3*r+1]*B[3] + A[3*r+2]*B[6];
        C[3*r+1] = A[3*r+0]*B[1] + A[3*r+1]*B[4] + A[3*r+2]*B[7];
        C[3*r+2] = A[3*r+0]*B[2] + A[3*r+1]*B[5] + A[3*r+2]*B[8];
    }
}

// R = Rx(a) @ Ry(b) @ Rz(c)  (pytorch3d euler_angles_to_matrix 'XYZ'), row-major
__device__ __forceinline__ void euler_rot(const float* __restrict__ ev, int i, float R[9]) {
    float a = ev[3*i+0], b = ev[3*i+1], c = ev[3*i+2];
    float sx, cx, sy, cy, sz, cz;
    __sincosf(a, &sx, &cx);
    __sincosf(b, &sy, &cy);
    __sincosf(c, &sz, &cz);
    R[0] = cy*cz;             R[1] = -cy*sz;            R[2] = sy;
    R[3] = sx*sy*cz + cx*sz;  R[4] = -sx*sy*sz + cx*cz; R[5] = -sx*cy;
    R[6] = -cx*sy*cz + sx*sz; R[7] = cx*sy*sz + sx*cz;  R[8] = cx*cy;
}

__global__ void __launch_bounds__(NB)
fk17_kernel(const float* __restrict__ euler, const float* __restrict__ blen,
            float* __restrict__ out, int n)
{
    __shared__ float s_o[NB * 51];  // output staging, odd stride -> conflict-free

    const int tid    = threadIdx.x;
    const int block0 = blockIdx.x * NB;
    const int nvalid = min(NB, n - block0);
    const int t      = block0 + tid;

    if (tid < nvalid) {
        // ---- direct per-thread loads: 12 + 4 independent float4s ----
        float ev[48];
        const float4* ge4 = (const float4*)(euler + (size_t)t * 48);
#pragma unroll
        for (int q = 0; q < 12; ++q) {
            float4 v = ge4[q];
            ev[4*q+0] = v.x; ev[4*q+1] = v.y; ev[4*q+2] = v.z; ev[4*q+3] = v.w;
        }
        float L[16];
        const float4* gb4 = (const float4*)(blen + (size_t)t * 16);
#pragma unroll
        for (int q = 0; q < 4; ++q) {
            float4 v = gb4[q];
            L[4*q+0] = v.x; L[4*q+1] = v.y; L[4*q+2] = v.z; L[4*q+3] = v.w;
        }

        float* o = s_o + tid * 51;
        float Ma[9], Mb[9], M8[9], R[9];
        float px, py, pz, p8x, p8y, p8z;

        // root (joint 0)
        o[0] = 0.f; o[1] = 0.f; o[2] = 0.f;

        // --- chain: 0 -> 1 -> 2 -> 3 (bones 0,1,2) ---
        euler_rot(ev, 0, Ma);                        // M1 = I @ R0
        px = L[0]*Ma[6]; py = L[0]*Ma[7]; pz = L[0]*Ma[8];
        o[3] = px; o[4] = py; o[5] = pz;
        euler_rot(ev, 1, R); mm3(Ma, R, Mb);
        px += L[1]*Mb[6]; py += L[1]*Mb[7]; pz += L[1]*Mb[8];
        o[6] = px; o[7] = py; o[8] = pz;
        euler_rot(ev, 2, R); mm3(Mb, R, Ma);
        px += L[2]*Ma[6]; py += L[2]*Ma[7]; pz += L[2]*Ma[8];
        o[9] = px; o[10] = py; o[11] = pz;

        // --- chain: 0 -> 4 -> 5 -> 6 (bones 3,4,5) ---
        euler_rot(ev, 3, Ma);
        px = L[3]*Ma[6]; py = L[3]*Ma[7]; pz = L[3]*Ma[8];
        o[12] = px; o[13] = py; o[14] = pz;
        euler_rot(ev, 4, R); mm3(Ma, R, Mb);
        px += L[4]*Mb[6]; py += L[4]*Mb[7]; pz += L[4]*Mb[8];
        o[15] = px; o[16] = py; o[17] = pz;
        euler_rot(ev, 5, R); mm3(Mb, R, Ma);
        px += L[5]*Ma[6]; py += L[5]*Ma[7]; pz += L[5]*Ma[8];
        o[18] = px; o[19] = py; o[20] = pz;

        // --- spine: 0 -> 7 -> 8 (bones 6,7) ---
        euler_rot(ev, 6, Ma);
        px = L[6]*Ma[6]; py = L[6]*Ma[7]; pz = L[6]*Ma[8];
        o[21] = px; o[22] = py; o[23] = pz;
        euler_rot(ev, 7, R); mm3(Ma, R, M8);         // M8 = accum at joint 8
        px += L[7]*M8[6]; py += L[7]*M8[7]; pz += L[7]*M8[8];
        o[24] = px; o[25] = py; o[26] = pz;
        p8x = px; p8y = py; p8z = pz;

        // --- branch: 8 -> 9 -> 10 (bones 8,9) ---
        euler_rot(ev, 8, R); mm3(M8, R, Ma);
        px = p8x + L[8]*Ma[6]; py = p8y + L[8]*Ma[7]; pz = p8z + L[8]*Ma[8];
        o[27] = px; o[28] = py; o[29] = pz;
        euler_rot(ev, 9, R); mm3(Ma, R, Mb);
        px += L[9]*Mb[6]; py += L[9]*Mb[7]; pz += L[9]*Mb[8];
        o[30] = px; o[31] = py; o[32] = pz;

        // --- branch: 8 -> 11 -> 12 -> 13 (bones 10,11,12) ---
        euler_rot(ev, 10, R); mm3(M8, R, Ma);
        px = p8x + L[10]*Ma[6]; py = p8y + L[10]*Ma[7]; pz = p8z + L[10]*Ma[8];
        o[33] = px; o[34] = py; o[35] = pz;
        euler_rot(ev, 11, R); mm3(Ma, R, Mb);
        px += L[11]*Mb[6]; py += L[11]*Mb[7]; pz += L[11]*Mb[8];
        o[36] = px; o[37] = py; o[38] = pz;
        euler_rot(ev, 12, R); mm3(Mb, R, Ma);
        px += L[12]*Ma[6]; py += L[12]*Ma[7]; pz += L[12]*Ma[8];
        o[39] = px; o[40] = py; o[41] = pz;

        // --- branch: 8 -> 14 -> 15 -> 16 (bones 13,14,15) ---
        euler_rot(ev, 13, R); mm3(M8, R, Ma);
        px = p8x + L[13]*Ma[6]; py = p8y + L[13]*Ma[7]; pz = p8z + L[13]*Ma[8];
        o[42] = px; o[43] = py; o[44] = pz;
        euler_rot(ev, 14, R); mm3(Ma, R, Mb);
        px += L[14]*Mb[6]; py += L[14]*Mb[7]; pz += L[14]*Mb[8];
        o[45] = px; o[46] = py; o[47] = pz;
        euler_rot(ev, 15, R); mm3(Mb, R, Ma);
        px += L[15]*Ma[6]; py += L[15]*Ma[7]; pz += L[15]*Ma[8];
        o[48] = px; o[49] = py; o[50] = pz;
    }
    __syncthreads();

    // ---- coalesced store: LDS flat -> global ----
    float* og = out + (size_t)block0 * 51;
    if (nvalid == NB) {
        const float4* so4 = (const float4*)s_o;
        float4*       og4 = (float4*)og;
        for (int i4 = tid; i4 < NB * 51 / 4; i4 += NB)  // 1632 float4s
            og4[i4] = so4[i4];
    } else {
        const int tot = nvalid * 51;
        for (int i = tid; i < tot; i += NB)
            og[i] = s_o[i];
    }
}

extern "C" void kernel_launch(void* const* d_in, const int* in_sizes, int n_in,
                              void* d_out, int out_size, void* d_ws, size_t ws_size,
                              hipStream_t stream) {
    const float* euler = (const float*)d_in[0];   // (N,16,3) fp32
    const float* blen  = (const float*)d_in[1];   // (N,16,1) fp32
    float* out = (float*)d_out;                   // (N,17,3) fp32

    const int n    = in_sizes[0] / 48;
    const int grid = (n + NB - 1) / NB;
    fk17_kernel<<<grid, NB, 0, stream>>>(euler, blen, out, n);
}